// Round 8
// baseline (2064.432 us; speedup 1.0000x reference)
//
#include <hip/hip_runtime.h>
#include <cmath>

#define B_  32
#define T_  250
#define E_  256
#define U_  1024
#define FU_ 4096   // 4*U
#define VK_ 1280   // virtual K = U + E  ( [rk0 ; k0] )
#define NT_ 40     // A/B k-tiles (32 h-tiles + 8 x-tiles)

typedef __attribute__((ext_vector_type(8)))  __bf16 bf16x8;
typedef __attribute__((ext_vector_type(4)))  float  f32x4;

__device__ __forceinline__ float sigf(float x) { return 1.f / (1.f + __expf(-x)); }

// ---------------------------------------------------------------------------
// One-time: transpose + hi/lo-split weights into MFMA B-fragment order
// (proven round 7). wfrag[((bi*40 + K)*64 + l)*8 + j].
// ---------------------------------------------------------------------------
__global__ __launch_bounds__(256) void wsplit_kernel(
    const float* __restrict__ rk0, const float* __restrict__ k0,
    __bf16* __restrict__ wfh, __bf16* __restrict__ wfl)
{
    __shared__ float tile[32][65];
    const int tid = threadIdx.x;
    const int jt  = blockIdx.x & 63;
    const int kt  = blockIdx.x >> 6;
    const int gk0 = kt * 32;
    const int j0  = jt * 64;

    {
        const int c = tid & 63, r4 = tid >> 6;
        #pragma unroll
        for (int i = 0; i < 8; ++i) {
            const int r  = r4 * 8 + i;
            const int gk = gk0 + r;
            const float* src = (gk < U_) ? (rk0 + (size_t)gk * FU_ + j0 + c)
                                         : (k0 + (size_t)(gk - U_) * FU_ + j0 + c);
            tile[r][c] = *src;
        }
    }
    __syncthreads();
    {
        const int j_loc = tid >> 2, kseg = tid & 3;
        bf16x8 hi, lo;
        #pragma unroll
        for (int i = 0; i < 8; ++i) {
            const float  v  = tile[kseg * 8 + i][j_loc];
            const __bf16 hv = (__bf16)v;
            hi[i] = hv;
            lo[i] = (__bf16)(v - (float)hv);
        }
        const int col = j0 + j_loc;
        const int g   = col >> 10;
        const int u   = col & 1023;
        const int bi  = u >> 2;
        const int c   = g * 4 + (u & 3);
        const int l   = kseg * 16 + c;
        const size_t off = (((size_t)bi * NT_ + kt) * 64 + l) * 8;
        *(bf16x8*)(wfh + off) = hi;
        *(bf16x8*)(wfl + off) = lo;
    }
}

// ---------------------------------------------------------------------------
// Seed x-fragments for step t into A-frag buffer (x-tiles K=32..39).
// 1 block x 256 threads; thread = (b = tid>>3, 32-k chunk kc=(tid&7)*32).
// Element (row=b, k): tile K=32+(k>>5), mt=b>>4, lane=((k>>3)&3)*16+(b&15),
// j=k&7 -> j contiguous => 16B vector stores.
// ---------------------------------------------------------------------------
__global__ __launch_bounds__(256) void xsplit_kernel(
    const int* __restrict__ tokens, const float* __restrict__ emb,
    __bf16* __restrict__ afh, __bf16* __restrict__ afl, int t)
{
    const int tid2 = threadIdx.x;
    const int b   = tid2 >> 3;
    const int kc  = (tid2 & 7) * 32;
    const int tok = tokens[b * T_ + t];
    const float* ep = emb + (size_t)tok * E_ + kc;
    const int Kt  = 32 + (kc >> 5);
    const int mt2 = b >> 4;
    #pragma unroll
    for (int g8 = 0; g8 < 4; ++g8) {
        bf16x8 hi, lo;
        #pragma unroll
        for (int j = 0; j < 8; ++j) {
            const float  v  = ep[g8 * 8 + j];
            const __bf16 hv = (__bf16)v;
            hi[j] = hv;
            lo[j] = (__bf16)(v - (float)hv);
        }
        const int lane2 = g8 * 16 + (b & 15);
        const size_t off = (((size_t)Kt * 2 + mt2) * 64 + lane2) * 8;
        *(bf16x8*)(afh + off) = hi;
        *(bf16x8*)(afl + off) = lo;
    }
}

// ---------------------------------------------------------------------------
// Fused LSTM step, launched 250x (stream order = grid barrier).
// Grid 256 x 512. Block bi = units [bi*4,bi*4+4) x 4 gates over full K=1280.
// GEMM phase: 40 UNIFORM fragment k-tiles (h 0..31 + x 32..39), all loads
// 16B/lane coalesced from A-frag ping-pong; 3 MFMA/tile (Markidis hi/lo).
// Tail: tid<128 -> pointwise (c update, h(t+1) frag write);
//       tid 128..383 -> gather+split emb for t+1 into A-frag[t+1] x-part
//       (x-path runs in otherwise-idle waves, off the critical GEMM).
// ---------------------------------------------------------------------------
__global__ __launch_bounds__(512) void step_fused(
    const __bf16* __restrict__ wfh, const __bf16* __restrict__ wfl,
    const float* __restrict__ b0,
    const __bf16* __restrict__ afh_r, const __bf16* __restrict__ afl_r,
    __bf16* __restrict__ afh_w, __bf16* __restrict__ afl_w,
    float* __restrict__ c_st,
    const int* __restrict__ tokens, const float* __restrict__ emb, int t)
{
    __shared__ float part[4][32][18];

    const int tid  = threadIdx.x;
    const int lane = tid & 63;
    const int w    = tid >> 6;          // 8 waves
    const int mt   = w & 1;             // m-tile (batches mt*16..mt*16+15)
    const int kq   = w >> 1;            // K-quarter (10 k-tiles)
    const int bi   = blockIdx.x;

    const __bf16* wbh = wfh + ((size_t)bi * NT_) * 512 + lane * 8;
    const __bf16* wbl = wfl + ((size_t)bi * NT_) * 512 + lane * 8;

    f32x4 acc_hh = {}, acc_lh = {}, acc_hl = {};

    #pragma unroll
    for (int s = 0; s < 10; ++s) {
        const int K = kq * 10 + s;      // uniform tile 0..39
        const bf16x8 wh = *(const bf16x8*)(wbh + (size_t)K * 512);
        const bf16x8 wl = *(const bf16x8*)(wbl + (size_t)K * 512);
        const size_t ao = ((size_t)(K * 2 + mt) * 64 + lane) * 8;
        const bf16x8 ah = *(const bf16x8*)(afh_r + ao);
        const bf16x8 al = *(const bf16x8*)(afl_r + ao);
        acc_hh = __builtin_amdgcn_mfma_f32_16x16x32_bf16(ah, wh, acc_hh, 0, 0, 0);
        acc_lh = __builtin_amdgcn_mfma_f32_16x16x32_bf16(al, wh, acc_lh, 0, 0, 0);
        acc_hl = __builtin_amdgcn_mfma_f32_16x16x32_bf16(ah, wl, acc_hl, 0, 0, 0);
    }

    // --- kq-partial exchange ---
    #pragma unroll
    for (int r = 0; r < 4; ++r) {
        const int row = mt * 16 + (lane >> 4) * 4 + r;
        part[kq][row][lane & 15] = acc_hh[r] + acc_lh[r] + acc_hl[r];
    }

    // --- idle-wave gather: pre-split x(t+1) into A-frag[t+1] x-part ---
    if (tid >= 128 && tid < 384 && t + 1 < T_) {
        const int tid2 = tid - 128;
        const int b2   = tid2 >> 3;
        const int kc   = (tid2 & 7) * 32;
        const int tok  = tokens[b2 * T_ + t + 1];
        const float* ep = emb + (size_t)tok * E_ + kc;
        const int Kt   = 32 + (kc >> 5);
        const int mt2  = b2 >> 4;
        #pragma unroll
        for (int g8 = 0; g8 < 4; ++g8) {
            bf16x8 hi, lo;
            #pragma unroll
            for (int j = 0; j < 8; ++j) {
                const float  v  = ep[g8 * 8 + j];
                const __bf16 hv = (__bf16)v;
                hi[j] = hv;
                lo[j] = (__bf16)(v - (float)hv);
            }
            const int lane2 = g8 * 16 + (b2 & 15);
            const size_t off = (((size_t)Kt * 2 + mt2) * 64 + lane2) * 8;
            *(bf16x8*)(afh_w + off) = hi;
            *(bf16x8*)(afl_w + off) = lo;
        }
    }
    __syncthreads();

    // --- pointwise: reduce kq partials, gates, c/h update ---
    if (tid < 128) {
        const int b  = tid >> 2, uu = tid & 3;
        const int u0 = bi * 4;
        float z[4];
        #pragma unroll
        for (int g = 0; g < 4; ++g) {
            const int c = g * 4 + uu;
            float s2 = b0[g * U_ + u0 + uu];
            #pragma unroll
            for (int q = 0; q < 4; ++q) s2 += part[q][b][c];
            z[g] = s2;
        }
        const float ii = sigf(z[0]), ff = sigf(z[1]);
        const float gg = tanhf(z[2]), oo = sigf(z[3]);
        const int ci = b * U_ + u0 + uu;
        const float cv = ff * c_st[ci] + ii * gg;
        c_st[ci] = cv;
        const float hv = oo * tanhf(cv);
        const __bf16 hb = (__bf16)hv;
        const int u = u0 + uu;
        const size_t fo = ((size_t)((u >> 5) * 2 + (b >> 4)) * 64
                           + ((u >> 3) & 3) * 16 + (b & 15)) * 8 + (u & 7);
        afh_w[fo] = hb;
        afl_w[fo] = (__bf16)(hv - (float)hb);
    }
}

// ---------------------------------------------------------------------------
// Cell-1 z (fp32, off critical path): Pc[b][col] = x_last @ k1 + b1.
// ---------------------------------------------------------------------------
__global__ __launch_bounds__(256) void cell1_gemm(
    const int* __restrict__ tokens, const float* __restrict__ emb,
    const float* __restrict__ k1, const float* __restrict__ b1,
    float* __restrict__ Pc)
{
    const int tid  = threadIdx.x;
    const int lane = tid & 63;
    const int warp = tid >> 6;
    const int j  = blockIdx.x;
    const int ct = j & 15, bg = j >> 4;
    const int b  = bg * 4 + warp;
    const int col = ct * 256 + lane * 4;
    const int tok = tokens[b * T_ + (T_ - 1)];
    const float* wp = k1 + col;
    const float* xp = emb + (size_t)tok * E_;
    float4 acc = *reinterpret_cast<const float4*>(b1 + col);
    #pragma unroll 4
    for (int k4 = 0; k4 < 64; ++k4) {
        const float4 x4 = *reinterpret_cast<const float4*>(xp + k4 * 4);
        const float4 w0 = *reinterpret_cast<const float4*>(wp + (size_t)(k4 * 4 + 0) * FU_);
        const float4 w1 = *reinterpret_cast<const float4*>(wp + (size_t)(k4 * 4 + 1) * FU_);
        const float4 w2 = *reinterpret_cast<const float4*>(wp + (size_t)(k4 * 4 + 2) * FU_);
        const float4 w3 = *reinterpret_cast<const float4*>(wp + (size_t)(k4 * 4 + 3) * FU_);
        acc.x = fmaf(x4.x, w0.x, acc.x); acc.y = fmaf(x4.x, w0.y, acc.y);
        acc.z = fmaf(x4.x, w0.z, acc.z); acc.w = fmaf(x4.x, w0.w, acc.w);
        acc.x = fmaf(x4.y, w1.x, acc.x); acc.y = fmaf(x4.y, w1.y, acc.y);
        acc.z = fmaf(x4.y, w1.z, acc.z); acc.w = fmaf(x4.y, w1.w, acc.w);
        acc.x = fmaf(x4.z, w2.x, acc.x); acc.y = fmaf(x4.z, w2.y, acc.y);
        acc.z = fmaf(x4.z, w2.z, acc.z); acc.w = fmaf(x4.z, w2.w, acc.w);
        acc.x = fmaf(x4.w, w3.x, acc.x); acc.y = fmaf(x4.w, w3.y, acc.y);
        acc.z = fmaf(x4.w, w3.z, acc.z); acc.w = fmaf(x4.w, w3.w, acc.w);
    }
    *reinterpret_cast<float4*>(Pc + (size_t)b * FU_ + col) = acc;
}

// ---------------------------------------------------------------------------
// Final: out[b] = sigmoid( h0.wout[0:U] + h1.wout[U:2U] + bout ).
// h0 from A-fragment layout bf16 hi+lo; h1 on the fly from Pc.
// ---------------------------------------------------------------------------
__global__ __launch_bounds__(256) void final_kernel(
    const __bf16* __restrict__ hfh, const __bf16* __restrict__ hfl,
    const float* __restrict__ Pc,
    const float* __restrict__ wout, const float* __restrict__ bout,
    float* __restrict__ out)
{
    const int b = blockIdx.x;
    const int tid = threadIdx.x;
    float s = 0.f;
    for (int u = tid; u < U_; u += 256) {
        const size_t fo = ((size_t)((u >> 5) * 2 + (b >> 4)) * 64
                           + ((u >> 3) & 3) * 16 + (b & 15)) * 8 + (u & 7);
        const float h0v = (float)hfh[fo] + (float)hfl[fo];
        const float zi = Pc[(size_t)b * FU_ + u];
        const float zg = Pc[(size_t)b * FU_ + 2 * U_ + u];
        const float zo = Pc[(size_t)b * FU_ + 3 * U_ + u];
        const float c1 = sigf(zi) * tanhf(zg);
        const float h1 = sigf(zo) * tanhf(c1);
        s += h0v * wout[u] + h1 * wout[U_ + u];
    }
    #pragma unroll
    for (int off = 32; off > 0; off >>= 1) s += __shfl_down(s, off, 64);
    __shared__ float partf[4];
    if ((tid & 63) == 0) partf[tid >> 6] = s;
    __syncthreads();
    if (tid == 0) {
        const float tot = partf[0] + partf[1] + partf[2] + partf[3] + bout[0];
        out[b] = 1.f / (1.f + __expf(-tot));
    }
}

extern "C" void kernel_launch(void* const* d_in, const int* in_sizes, int n_in,
                              void* d_out, int out_size, void* d_ws, size_t ws_size,
                              hipStream_t stream) {
    const int*   tokens = (const int*)  d_in[0];
    const float* emb    = (const float*)d_in[1];
    const float* k0     = (const float*)d_in[2];
    const float* rk0    = (const float*)d_in[3];
    const float* b0     = (const float*)d_in[4];
    const float* k1     = (const float*)d_in[5];
    // d_in[6] = rk1 unused: cell 1 runs from zero state.
    const float* b1     = (const float*)d_in[7];
    const float* wout   = (const float*)d_in[8];
    const float* bout   = (const float*)d_in[9];
    float* out = (float*)d_out;

    const size_t BU   = (size_t)B_ * U_;       // 32768
    const size_t BFU  = (size_t)B_ * FU_;      // 131072
    const size_t AFSZ = (size_t)NT_ * 2 * 64 * 8;  // 40960 elems (80 KB)
    const size_t WSZ  = (size_t)FU_ * VK_;     // 5242880

    float*  c    = (float*)d_ws;               // [32][1024] f32   (128 KB)
    __bf16* af0h = (__bf16*)(c + BU);          // A-frag parity0 hi (80 KB)
    __bf16* af0l = af0h + AFSZ;                // A-frag parity0 lo
    __bf16* af1h = af0l + AFSZ;                // A-frag parity1 hi
    __bf16* af1l = af1h + AFSZ;                // A-frag parity1 lo
    __bf16* wfh  = af1l + AFSZ;                // W frag hi (10.5 MB)
    __bf16* wfl  = wfh + WSZ;                  // W frag lo (10.5 MB)
    float*  Pc   = (float*)(wfl + WSZ);        // [32][4096] f32  (512 KB)
    // ws use ~= 21.6 MB

    // zero c + A-frag parity0 (contiguous) every call; x-part of parity0 is
    // then filled by xsplit. All other state fully rewritten before reads.
    hipMemsetAsync(c, 0, BU * sizeof(float) + 2 * AFSZ * sizeof(__bf16), stream);

    wsplit_kernel<<<2560, 256, 0, stream>>>(rk0, k0, wfh, wfl);
    xsplit_kernel<<<1, 256, 0, stream>>>(tokens, emb, af0h, af0l, 0);
    cell1_gemm<<<128, 256, 0, stream>>>(tokens, emb, k1, b1, Pc);

    for (int t = 0; t < T_; ++t) {
        const __bf16* arh = (t & 1) ? af1h : af0h;
        const __bf16* arl = (t & 1) ? af1l : af0l;
        __bf16* awh = (t & 1) ? af0h : af1h;
        __bf16* awl = (t & 1) ? af0l : af1l;
        step_fused<<<256, 512, 0, stream>>>(wfh, wfl, b0, arh, arl, awh, awl,
                                            c, tokens, emb, t);
    }
    // T_=250 even: t=249 writes parity 0 -> final h in af0.

    final_kernel<<<B_, 256, 0, stream>>>(af0h, af0l, Pc, wout, bout, out);
}

// Round 9
// 1763.129 us; speedup vs baseline: 1.1709x; 1.1709x over previous
//
#include <hip/hip_runtime.h>
#include <cmath>

#define B_  32
#define T_  250
#define E_  256
#define U_  1024
#define FU_ 4096   // 4*U
#define VK_ 1280   // virtual K = U + E  ( [rk0 ; k0] )
#define NT_ 40     // A/B k-tiles (32 h-tiles + 8 x-tiles)

typedef __attribute__((ext_vector_type(8)))  __bf16 bf16x8;
typedef __attribute__((ext_vector_type(4)))  float  f32x4;

__device__ __forceinline__ float sigf(float x) { return 1.f / (1.f + __expf(-x)); }

// ---------------------------------------------------------------------------
// One-time: transpose + hi/lo-split weights into MFMA B-fragment order
// (proven rounds 7-8). wfrag[((bi*40 + K)*64 + l)*8 + j].
// ---------------------------------------------------------------------------
__global__ __launch_bounds__(256) void wsplit_kernel(
    const float* __restrict__ rk0, const float* __restrict__ k0,
    __bf16* __restrict__ wfh, __bf16* __restrict__ wfl)
{
    __shared__ float tile[32][65];
    const int tid = threadIdx.x;
    const int jt  = blockIdx.x & 63;
    const int kt  = blockIdx.x >> 6;
    const int gk0 = kt * 32;
    const int j0  = jt * 64;

    {
        const int c = tid & 63, r4 = tid >> 6;
        #pragma unroll
        for (int i = 0; i < 8; ++i) {
            const int r  = r4 * 8 + i;
            const int gk = gk0 + r;
            const float* src = (gk < U_) ? (rk0 + (size_t)gk * FU_ + j0 + c)
                                         : (k0 + (size_t)(gk - U_) * FU_ + j0 + c);
            tile[r][c] = *src;
        }
    }
    __syncthreads();
    {
        const int j_loc = tid >> 2, kseg = tid & 3;
        bf16x8 hi, lo;
        #pragma unroll
        for (int i = 0; i < 8; ++i) {
            const float  v  = tile[kseg * 8 + i][j_loc];
            const __bf16 hv = (__bf16)v;
            hi[i] = hv;
            lo[i] = (__bf16)(v - (float)hv);
        }
        const int col = j0 + j_loc;
        const int g   = col >> 10;
        const int u   = col & 1023;
        const int bi  = u >> 2;
        const int c   = g * 4 + (u & 3);
        const int l   = kseg * 16 + c;
        const size_t off = (((size_t)bi * NT_ + kt) * 64 + l) * 8;
        *(bf16x8*)(wfh + off) = hi;
        *(bf16x8*)(wfl + off) = lo;
    }
}

// ---------------------------------------------------------------------------
// Seed x-fragments for step 0 (x-tiles K=32..39). 1 block x 256 threads;
// thread = (b = tid>>3, 32-k chunk kc=(tid&7)*32).
// ---------------------------------------------------------------------------
__global__ __launch_bounds__(256) void xsplit_kernel(
    const int* __restrict__ tokens, const float* __restrict__ emb,
    __bf16* __restrict__ afh, __bf16* __restrict__ afl, int t)
{
    const int tid2 = threadIdx.x;
    const int b   = tid2 >> 3;
    const int kc  = (tid2 & 7) * 32;
    const int tok = tokens[b * T_ + t];
    const float* ep = emb + (size_t)tok * E_ + kc;
    const int Kt  = 32 + (kc >> 5);
    const int mt2 = b >> 4;
    #pragma unroll
    for (int g8 = 0; g8 < 4; ++g8) {
        bf16x8 hi, lo;
        #pragma unroll
        for (int j = 0; j < 8; ++j) {
            const float  v  = ep[g8 * 8 + j];
            const __bf16 hv = (__bf16)v;
            hi[j] = hv;
            lo[j] = (__bf16)(v - (float)hv);
        }
        const int lane2 = g8 * 16 + (b & 15);
        const size_t off = (((size_t)Kt * 2 + mt2) * 64 + lane2) * 8;
        *(bf16x8*)(afh + off) = hi;
        *(bf16x8*)(afl + off) = lo;
    }
}

// ---------------------------------------------------------------------------
// Fused LSTM step, launched 250x (stream order = grid barrier).
// Grid 256 x 512. Block bi = units [bi*4,bi*4+4) x 4 gates over full K=1280.
// GEMM: 40 UNIFORM fragment k-tiles, 16B/lane coalesced loads, 3 MFMA/tile
// (Markidis hi/lo). Tail: tid<128 -> pointwise;
// x(t+1) prefetch PARTITIONED across blocks 0..7 (32 threads each, batches
// [4bi,4bi+4)) -- round 8 ran it redundantly in all 256 blocks, regression.
// ---------------------------------------------------------------------------
__global__ __launch_bounds__(512) void step_fused(
    const __bf16* __restrict__ wfh, const __bf16* __restrict__ wfl,
    const float* __restrict__ b0,
    const __bf16* __restrict__ afh_r, const __bf16* __restrict__ afl_r,
    __bf16* __restrict__ afh_w, __bf16* __restrict__ afl_w,
    float* __restrict__ c_st,
    const int* __restrict__ tokens, const float* __restrict__ emb, int t)
{
    __shared__ float part[4][32][18];

    const int tid  = threadIdx.x;
    const int lane = tid & 63;
    const int w    = tid >> 6;          // 8 waves
    const int mt   = w & 1;             // m-tile (batches mt*16..mt*16+15)
    const int kq   = w >> 1;            // K-quarter (10 k-tiles)
    const int bi   = blockIdx.x;

    const __bf16* wbh = wfh + ((size_t)bi * NT_) * 512 + lane * 8;
    const __bf16* wbl = wfl + ((size_t)bi * NT_) * 512 + lane * 8;

    f32x4 acc_hh = {}, acc_lh = {}, acc_hl = {};

    #pragma unroll
    for (int s = 0; s < 10; ++s) {
        const int K = kq * 10 + s;      // uniform tile 0..39
        const bf16x8 wh = *(const bf16x8*)(wbh + (size_t)K * 512);
        const bf16x8 wl = *(const bf16x8*)(wbl + (size_t)K * 512);
        const size_t ao = ((size_t)(K * 2 + mt) * 64 + lane) * 8;
        const bf16x8 ah = *(const bf16x8*)(afh_r + ao);
        const bf16x8 al = *(const bf16x8*)(afl_r + ao);
        acc_hh = __builtin_amdgcn_mfma_f32_16x16x32_bf16(ah, wh, acc_hh, 0, 0, 0);
        acc_lh = __builtin_amdgcn_mfma_f32_16x16x32_bf16(al, wh, acc_lh, 0, 0, 0);
        acc_hl = __builtin_amdgcn_mfma_f32_16x16x32_bf16(ah, wl, acc_hl, 0, 0, 0);
    }

    // --- kq-partial exchange ---
    #pragma unroll
    for (int r = 0; r < 4; ++r) {
        const int row = mt * 16 + (lane >> 4) * 4 + r;
        part[kq][row][lane & 15] = acc_hh[r] + acc_lh[r] + acc_hl[r];
    }

    // --- x(t+1) prefetch: blocks 0..7 only, 32 threads each (non-redundant)
    if (bi < 8 && tid >= 128 && tid < 160 && t + 1 < T_) {
        const int tid2 = bi * 32 + (tid - 128);   // 0..255 global partition
        const int b2   = tid2 >> 3;
        const int kc   = (tid2 & 7) * 32;
        const int tok  = tokens[b2 * T_ + t + 1];
        const float* ep = emb + (size_t)tok * E_ + kc;
        const int Kt   = 32 + (kc >> 5);
        const int mt2  = b2 >> 4;
        #pragma unroll
        for (int g8 = 0; g8 < 4; ++g8) {
            bf16x8 hi, lo;
            #pragma unroll
            for (int j = 0; j < 8; ++j) {
                const float  v  = ep[g8 * 8 + j];
                const __bf16 hv = (__bf16)v;
                hi[j] = hv;
                lo[j] = (__bf16)(v - (float)hv);
            }
            const int lane2 = g8 * 16 + (b2 & 15);
            const size_t off = (((size_t)Kt * 2 + mt2) * 64 + lane2) * 8;
            *(bf16x8*)(afh_w + off) = hi;
            *(bf16x8*)(afl_w + off) = lo;
        }
    }
    __syncthreads();

    // --- pointwise: reduce kq partials, gates, c/h update ---
    if (tid < 128) {
        const int b  = tid >> 2, uu = tid & 3;
        const int u0 = bi * 4;
        float z[4];
        #pragma unroll
        for (int g = 0; g < 4; ++g) {
            const int c = g * 4 + uu;
            float s2 = b0[g * U_ + u0 + uu];
            #pragma unroll
            for (int q = 0; q < 4; ++q) s2 += part[q][b][c];
            z[g] = s2;
        }
        const float ii = sigf(z[0]), ff = sigf(z[1]);
        const float gg = tanhf(z[2]), oo = sigf(z[3]);
        const int ci = b * U_ + u0 + uu;
        const float cv = ff * c_st[ci] + ii * gg;
        c_st[ci] = cv;
        const float hv = oo * tanhf(cv);
        const __bf16 hb = (__bf16)hv;
        const int u = u0 + uu;
        const size_t fo = ((size_t)((u >> 5) * 2 + (b >> 4)) * 64
                           + ((u >> 3) & 3) * 16 + (b & 15)) * 8 + (u & 7);
        afh_w[fo] = hb;
        afl_w[fo] = (__bf16)(hv - (float)hb);
    }
}

// ---------------------------------------------------------------------------
// Cell-1 z (fp32, off critical path): Pc[b][col] = x_last @ k1 + b1.
// ---------------------------------------------------------------------------
__global__ __launch_bounds__(256) void cell1_gemm(
    const int* __restrict__ tokens, const float* __restrict__ emb,
    const float* __restrict__ k1, const float* __restrict__ b1,
    float* __restrict__ Pc)
{
    const int tid  = threadIdx.x;
    const int lane = tid & 63;
    const int warp = tid >> 6;
    const int j  = blockIdx.x;
    const int ct = j & 15, bg = j >> 4;
    const int b  = bg * 4 + warp;
    const int col = ct * 256 + lane * 4;
    const int tok = tokens[b * T_ + (T_ - 1)];
    const float* wp = k1 + col;
    const float* xp = emb + (size_t)tok * E_;
    float4 acc = *reinterpret_cast<const float4*>(b1 + col);
    #pragma unroll 4
    for (int k4 = 0; k4 < 64; ++k4) {
        const float4 x4 = *reinterpret_cast<const float4*>(xp + k4 * 4);
        const float4 w0 = *reinterpret_cast<const float4*>(wp + (size_t)(k4 * 4 + 0) * FU_);
        const float4 w1 = *reinterpret_cast<const float4*>(wp + (size_t)(k4 * 4 + 1) * FU_);
        const float4 w2 = *reinterpret_cast<const float4*>(wp + (size_t)(k4 * 4 + 2) * FU_);
        const float4 w3 = *reinterpret_cast<const float4*>(wp + (size_t)(k4 * 4 + 3) * FU_);
        acc.x = fmaf(x4.x, w0.x, acc.x); acc.y = fmaf(x4.x, w0.y, acc.y);
        acc.z = fmaf(x4.x, w0.z, acc.z); acc.w = fmaf(x4.x, w0.w, acc.w);
        acc.x = fmaf(x4.y, w1.x, acc.x); acc.y = fmaf(x4.y, w1.y, acc.y);
        acc.z = fmaf(x4.y, w1.z, acc.z); acc.w = fmaf(x4.y, w1.w, acc.w);
        acc.x = fmaf(x4.z, w2.x, acc.x); acc.y = fmaf(x4.z, w2.y, acc.y);
        acc.z = fmaf(x4.z, w2.z, acc.z); acc.w = fmaf(x4.z, w2.w, acc.w);
        acc.x = fmaf(x4.w, w3.x, acc.x); acc.y = fmaf(x4.w, w3.y, acc.y);
        acc.z = fmaf(x4.w, w3.z, acc.z); acc.w = fmaf(x4.w, w3.w, acc.w);
    }
    *reinterpret_cast<float4*>(Pc + (size_t)b * FU_ + col) = acc;
}

// ---------------------------------------------------------------------------
// Final: out[b] = sigmoid( h0.wout[0:U] + h1.wout[U:2U] + bout ).
// h0 from A-fragment layout bf16 hi+lo; h1 on the fly from Pc.
// ---------------------------------------------------------------------------
__global__ __launch_bounds__(256) void final_kernel(
    const __bf16* __restrict__ hfh, const __bf16* __restrict__ hfl,
    const float* __restrict__ Pc,
    const float* __restrict__ wout, const float* __restrict__ bout,
    float* __restrict__ out)
{
    const int b = blockIdx.x;
    const int tid = threadIdx.x;
    float s = 0.f;
    for (int u = tid; u < U_; u += 256) {
        const size_t fo = ((size_t)((u >> 5) * 2 + (b >> 4)) * 64
                           + ((u >> 3) & 3) * 16 + (b & 15)) * 8 + (u & 7);
        const float h0v = (float)hfh[fo] + (float)hfl[fo];
        const float zi = Pc[(size_t)b * FU_ + u];
        const float zg = Pc[(size_t)b * FU_ + 2 * U_ + u];
        const float zo = Pc[(size_t)b * FU_ + 3 * U_ + u];
        const float c1 = sigf(zi) * tanhf(zg);
        const float h1 = sigf(zo) * tanhf(c1);
        s += h0v * wout[u] + h1 * wout[U_ + u];
    }
    #pragma unroll
    for (int off = 32; off > 0; off >>= 1) s += __shfl_down(s, off, 64);
    __shared__ float partf[4];
    if ((tid & 63) == 0) partf[tid >> 6] = s;
    __syncthreads();
    if (tid == 0) {
        const float tot = partf[0] + partf[1] + partf[2] + partf[3] + bout[0];
        out[b] = 1.f / (1.f + __expf(-tot));
    }
}

extern "C" void kernel_launch(void* const* d_in, const int* in_sizes, int n_in,
                              void* d_out, int out_size, void* d_ws, size_t ws_size,
                              hipStream_t stream) {
    const int*   tokens = (const int*)  d_in[0];
    const float* emb    = (const float*)d_in[1];
    const float* k0     = (const float*)d_in[2];
    const float* rk0    = (const float*)d_in[3];
    const float* b0     = (const float*)d_in[4];
    const float* k1     = (const float*)d_in[5];
    // d_in[6] = rk1 unused: cell 1 runs from zero state.
    const float* b1     = (const float*)d_in[7];
    const float* wout   = (const float*)d_in[8];
    const float* bout   = (const float*)d_in[9];
    float* out = (float*)d_out;

    const size_t BU   = (size_t)B_ * U_;       // 32768
    const size_t BFU  = (size_t)B_ * FU_;      // 131072
    const size_t AFSZ = (size_t)NT_ * 2 * 64 * 8;  // 40960 elems (80 KB)
    const size_t WSZ  = (size_t)FU_ * VK_;     // 5242880

    float*  c    = (float*)d_ws;               // [32][1024] f32   (128 KB)
    __bf16* af0h = (__bf16*)(c + BU);          // A-frag parity0 hi (80 KB)
    __bf16* af0l = af0h + AFSZ;                // A-frag parity0 lo
    __bf16* af1h = af0l + AFSZ;                // A-frag parity1 hi
    __bf16* af1l = af1h + AFSZ;                // A-frag parity1 lo
    __bf16* wfh  = af1l + AFSZ;                // W frag hi (10.5 MB)
    __bf16* wfl  = wfh + WSZ;                  // W frag lo (10.5 MB)
    float*  Pc   = (float*)(wfl + WSZ);        // [32][4096] f32  (512 KB)
    // ws use ~= 21.6 MB

    // zero c + A-frag parity0 (contiguous) every call; x-part of parity0 is
    // then filled by xsplit. All other state fully rewritten before reads.
    hipMemsetAsync(c, 0, BU * sizeof(float) + 2 * AFSZ * sizeof(__bf16), stream);

    wsplit_kernel<<<2560, 256, 0, stream>>>(rk0, k0, wfh, wfl);
    xsplit_kernel<<<1, 256, 0, stream>>>(tokens, emb, af0h, af0l, 0);
    cell1_gemm<<<128, 256, 0, stream>>>(tokens, emb, k1, b1, Pc);

    for (int t = 0; t < T_; ++t) {
        const __bf16* arh = (t & 1) ? af1h : af0h;
        const __bf16* arl = (t & 1) ? af1l : af0l;
        __bf16* awh = (t & 1) ? af0h : af1h;
        __bf16* awl = (t & 1) ? af0l : af1l;
        step_fused<<<256, 512, 0, stream>>>(wfh, wfl, b0, arh, arl, awh, awl,
                                            c, tokens, emb, t);
    }
    // T_=250 even: t=249 writes parity 0 -> final h in af0.

    final_kernel<<<B_, 256, 0, stream>>>(af0h, af0l, Pc, wout, bout, out);
}